// Round 9
// baseline (244.100 us; speedup 1.0000x reference)
//
#include <hip/hip_runtime.h>
#include <math.h>

// DigitCaps dynamic routing, MI355X. Round 8: pre-transposed fp16 W in
// workspace; main kernel reads W directly from global (no LDS, no barriers).
// u[B=128, R=864, I=4] f32, W[1, J=166, R=864, O=8, I=4] f32 -> v[128,166,8] f32.
//
// Rounds 1-7 learned: LDS staging only existed because W's [r][o][i] layout
// gives 128 B lane stride. Round 8 fixes the layout once per launch:
//   pre-kernel 1: W [J][R][O][I] f32 -> W' [J][O][R] packed fp16 (uint2, 9.2 MB in d_ws)
//   pre-kernel 2: u [B][R][I] f32   -> u' [B][R]   packed fp16 (uint2, 0.9 MB in d_ws)
// Main kernel, one wave per (b,j): lane owns r = lane+64k; W'[j][o][r] loads
// are 8 B/lane coalesced (512 B/instruction). W'[j] = 55 KB reused by 128
// b-waves through L1/L2 (same-j blocks adjacent in grid). No __syncthreads
// anywhere; occupancy VGPR-limited only.
// u_hat packed fp16 pairs in uint32 regs (plain unrolled loop, no barriers ->
// SROA safe; WRITE_SIZE is the spill tripwire). Routing: b_r = <u_hat, V> via
// v_dot2_f32_f16, V = running sum of v's; no softmax max-pass.

#define BB 128
#define JJ 166
#define RR 864
#define OO 8
#define KMAX 14            // ceil(864/64); k=13 has only lanes 0..31 valid

#define WP_U2   (JJ * OO * RR)          // 1,147,392 uint2 = 9,179,136 B
#define UP_OFF  (WP_U2 * 8)             // byte offset of u' in d_ws

typedef __fp16 h2v __attribute__((ext_vector_type(2)));

__device__ __forceinline__ uint32_t pack2(float a, float b) {
    return __builtin_bit_cast(uint32_t, __builtin_amdgcn_cvt_pkrtz(a, b));
}
__device__ __forceinline__ h2v bc_h2(uint32_t u) {
    return __builtin_bit_cast(h2v, u);
}
__device__ __forceinline__ float lo_f(uint32_t u) {
    return (float)__builtin_bit_cast(h2v, u).x;
}
__device__ __forceinline__ float hi_f(uint32_t u) {
    return (float)__builtin_bit_cast(h2v, u).y;
}

__device__ __forceinline__ float wave_sum(float v) {
#pragma unroll
    for (int m = 32; m >= 1; m >>= 1) v += __shfl_xor(v, m, 64);
    return v;
}

// ---- pre-kernel 1: W [J][R][O][I] f32 -> W' [J][O][R] fp16-pair uint2 ----
// t = (j*R + r)*O + o  -> coalesced float4 reads; writes touch 8 lines/wave.
__global__ __launch_bounds__(256) void pack_W_kernel(
    const float4* __restrict__ W4, uint2* __restrict__ Wp) {
    const int t = blockIdx.x * 256 + threadIdx.x;  // < J*R*O
    const float4 w = W4[t];
    const int o = t % OO;
    const int jr = t / OO;
    const int r = jr % RR;
    const int j = jr / RR;
    Wp[(j * OO + o) * RR + r] = make_uint2(pack2(w.x, w.y), pack2(w.z, w.w));
}

// ---- pre-kernel 2: u [B][R][I] f32 -> u' [B][R] fp16-pair uint2 ----
__global__ __launch_bounds__(256) void pack_u_kernel(
    const float4* __restrict__ u4, uint2* __restrict__ up) {
    const int t = blockIdx.x * 256 + threadIdx.x;  // < B*R
    const float4 uu = u4[t];
    up[t] = make_uint2(pack2(uu.x, uu.y), pack2(uu.z, uu.w));
}

__global__ __launch_bounds__(256) void digitcaps_kernel(
    const uint2* __restrict__ Wp, const uint2* __restrict__ up,
    float* __restrict__ out) {
    const int tid = threadIdx.x;
    const int lane = tid & 63;
    const int wave = tid >> 6;

    // 32 blocks per j; consecutive blocks share j for L1/L2 locality.
    const int j = blockIdx.x >> 5;
    const int b = ((blockIdx.x & 31) << 2) + wave;

    uint32_t uh[KMAX][4];  // u_hat packed fp16 pairs

    // ---- u_hat straight from global: coalesced 8 B/lane reads ----
    const int wjbase = j * (OO * RR) + lane;  // + o*RR + kl*64
    const int ubase = b * RR + lane;          // + kl*64
#pragma unroll
    for (int kl = 0; kl < KMAX; ++kl) {
        const bool valid = (kl < KMAX - 1) || (lane < 32);
        const int koff = kl << 6;
        const int uoff = valid ? koff : 0;  // clamp OOB lanes to a safe addr
        const uint2 uu = up[ubase + uoff];
        float d[OO];
#pragma unroll
        for (int o = 0; o < OO; ++o) {
            const uint2 ww = Wp[wjbase + o * RR + uoff];
            float t0 = __builtin_amdgcn_fdot2(bc_h2(ww.x), bc_h2(uu.x), 0.0f, false);
            d[o] = __builtin_amdgcn_fdot2(bc_h2(ww.y), bc_h2(uu.y), t0, false);
        }
#pragma unroll
        for (int o2 = 0; o2 < 4; ++o2)
            uh[kl][o2] = valid ? pack2(d[2 * o2], d[2 * o2 + 1]) : 0u;
    }

    float V[OO];  // running sum of past v's (b_r = <uhat_r, V>)
    float v[OO];

    // ---- iteration 0: b=0 -> c uniform = 1/R (packed fp16 partial sums) ----
    {
        h2v accp[4];
#pragma unroll
        for (int o2 = 0; o2 < 4; ++o2) accp[o2] = bc_h2(uh[0][o2]);
#pragma unroll
        for (int k = 1; k < KMAX; ++k)
#pragma unroll
            for (int o2 = 0; o2 < 4; ++o2) accp[o2] += bc_h2(uh[k][o2]);

        float s[OO];
#pragma unroll
        for (int o2 = 0; o2 < 4; ++o2) {
            s[2 * o2]     = wave_sum((float)accp[o2].x) * (1.0f / (float)RR);
            s[2 * o2 + 1] = wave_sum((float)accp[o2].y) * (1.0f / (float)RR);
        }
        float n2 = 0.0f;
#pragma unroll
        for (int o = 0; o < OO; ++o) n2 += s[o] * s[o];
        const float scale = sqrtf(n2) / (1.0f + n2);
#pragma unroll
        for (int o = 0; o < OO; ++o) { v[o] = s[o] * scale; V[o] = v[o]; }
    }

    // ---- iterations 1 and 2 ----
#pragma unroll
    for (int it = 1; it < 3; ++it) {
        uint32_t Vp[4];
#pragma unroll
        for (int o2 = 0; o2 < 4; ++o2)
            Vp[o2] = pack2(V[2 * o2], V[2 * o2 + 1]);

        float zp = 0.0f;
        float sp[OO];
#pragma unroll
        for (int o = 0; o < OO; ++o) sp[o] = 0.0f;

#pragma unroll
        for (int k = 0; k < KMAX; ++k) {
            float br = 0.0f;
#pragma unroll
            for (int o2 = 0; o2 < 4; ++o2)
                br = __builtin_amdgcn_fdot2(bc_h2(uh[k][o2]), bc_h2(Vp[o2]),
                                            br, false);
            // mask invalid routes (k==13, lane>=32): exp(0)=1 would pollute Z
            const float e = (k < KMAX - 1 || lane < 32) ? __expf(br) : 0.0f;
            zp += e;
#pragma unroll
            for (int o2 = 0; o2 < 4; ++o2) {
                sp[2 * o2]     = fmaf(e, lo_f(uh[k][o2]), sp[2 * o2]);
                sp[2 * o2 + 1] = fmaf(e, hi_f(uh[k][o2]), sp[2 * o2 + 1]);
            }
        }
        const float invZ = 1.0f / wave_sum(zp);

        float s[OO];
#pragma unroll
        for (int o = 0; o < OO; ++o) s[o] = wave_sum(sp[o]) * invZ;

        float n2 = 0.0f;
#pragma unroll
        for (int o = 0; o < OO; ++o) n2 += s[o] * s[o];
        const float scale = sqrtf(n2) / (1.0f + n2);
#pragma unroll
        for (int o = 0; o < OO; ++o) v[o] = s[o] * scale;

        if (it < 2) {
#pragma unroll
            for (int o = 0; o < OO; ++o) V[o] += v[o];
        }
    }

    // ---- write out[b][j][o]; v replicated across lanes after butterflies ----
    float outv = 0.0f;
#pragma unroll
    for (int o = 0; o < OO; ++o)
        if (lane == o) outv = v[o];
    if (lane < OO) out[(b * JJ + j) * OO + lane] = outv;
}

extern "C" void kernel_launch(void* const* d_in, const int* in_sizes, int n_in,
                              void* d_out, int out_size, void* d_ws, size_t ws_size,
                              hipStream_t stream) {
    const float* u = (const float*)d_in[0];  // [128, 864, 4]
    const float* W = (const float*)d_in[1];  // [1, 166, 864, 8, 4]
    float* out = (float*)d_out;              // [128, 166, 8]

    uint2* Wp = (uint2*)d_ws;                              // 9,179,136 B
    uint2* up = (uint2*)((char*)d_ws + UP_OFF);            // +884,736 B (needs ~10.1 MB ws)

    // pre-pack (memory-bound, ~5 us total)
    pack_W_kernel<<<(JJ * RR * OO) / 256, 256, 0, stream>>>((const float4*)W, Wp);
    pack_u_kernel<<<(BB * RR) / 256, 256, 0, stream>>>((const float4*)u, up);

    const int grid = JJ * (BB / 4);  // 5312 blocks, 4 waves each
    digitcaps_kernel<<<grid, 256, 0, stream>>>(Wp, up, out);
}

// Round 10
// 149.919 us; speedup vs baseline: 1.6282x; 1.6282x over previous
//
#include <hip/hip_runtime.h>
#include <math.h>

// DigitCaps dynamic routing, MI355X. Round 9: round-7 LDS pipeline + round-8
// pre-packed W' layout + global_load_lds DMA staging (no transpose, no cvt,
// no VGPR round-trip in staging).
// u[B=128, R=864, I=4] f32, W[1, J=166, R=864, O=8, I=4] f32 -> v[128,166,8] f32.
//
// Round-8 post-mortem: direct global compute reads = L2-latency-bound (195us,
// VALU 24%). Compute must read LDS; the staging *overhead* is what round 9
// deletes:
//   pre-kernel: W -> W'[j][o][r] packed-fp16 uint2 (9.2 MB ws), u -> u'[b][r]
//   main: chunk (256 routes x 8 o = 16 KB) DMA'd straight into LDS via
//   __builtin_amdgcn_global_load_lds (16 B/lane; LDS dest = wave-uniform base
//   + lane*16 — layout is exactly lane-order-contiguous). Double-buffered,
//   one barrier per chunk; barrier's vmcnt drain is the only wait.
// Compute/routing as round 7: u_hat packed fp16 in uint32 regs (constant
// indices via literal-macro expansion — round-4 spill lesson), dot2 u_hat and
// logits, V = running sum of v's, no softmax max-pass.

#define BB 128
#define JJ 166
#define RR 864
#define OO 8
#define KMAX 14            // ceil(864/64); k=13 has only lanes 0..31 valid
#define CH_U2 2048         // uint2 per chunk: 256 routes * 8 o

typedef __fp16 h2v __attribute__((ext_vector_type(2)));

__device__ __forceinline__ uint32_t pack2(float a, float b) {
    return __builtin_bit_cast(uint32_t, __builtin_amdgcn_cvt_pkrtz(a, b));
}
__device__ __forceinline__ h2v bc_h2(uint32_t u) {
    return __builtin_bit_cast(h2v, u);
}
__device__ __forceinline__ float lo_f(uint32_t u) {
    return (float)__builtin_bit_cast(h2v, u).x;
}
__device__ __forceinline__ float hi_f(uint32_t u) {
    return (float)__builtin_bit_cast(h2v, u).y;
}

__device__ __forceinline__ float wave_sum(float v) {
#pragma unroll
    for (int m = 32; m >= 1; m >>= 1) v += __shfl_xor(v, m, 64);
    return v;
}

// ---- pre-kernel: pack W -> W'[j][o][r] and u -> u'[b][r] (fp16 pairs) ----
#define WBLOCKS 4482   // J*R*O/256
#define UBLOCKS 432    // B*R/256
__global__ __launch_bounds__(256) void pack_kernel(
    const float4* __restrict__ W4, const float4* __restrict__ u4,
    uint2* __restrict__ Wp, uint2* __restrict__ up) {
    if (blockIdx.x < WBLOCKS) {
        const int t = blockIdx.x * 256 + threadIdx.x;  // < J*R*O
        const float4 w = W4[t];
        const int o = t & 7;
        const int jr = t >> 3;
        const int r = jr % RR;
        const int j = jr / RR;
        // 64 B-sector-aligned 8-element row segments -> full-sector writes
        Wp[(j * OO + o) * RR + r] = make_uint2(pack2(w.x, w.y), pack2(w.z, w.w));
    } else {
        const int t = (blockIdx.x - WBLOCKS) * 256 + threadIdx.x;  // < B*R
        const float4 uu = u4[t];
        up[t] = make_uint2(pack2(uu.x, uu.y), pack2(uu.z, uu.w));
    }
}

__global__ __launch_bounds__(256) void digitcaps_kernel(
    const uint2* __restrict__ Wp, const uint2* __restrict__ up,
    float* __restrict__ out) {
    const int tid = threadIdx.x;
    const int lane = tid & 63;
    const int wave = tid >> 6;

    // 32 blocks per j; consecutive blocks share j for L2 locality.
    const int j = blockIdx.x >> 5;
    const int b = ((blockIdx.x & 31) << 2) + wave;

    // two chunk buffers, [o][rl] rows of 256 uint2, lane-order contiguous
    __shared__ uint2 wlds[2][CH_U2];  // 2 x 16,384 B

    uint32_t uh[KMAX][4];  // u_hat packed fp16 pairs; constant-indexed only

    // ---- DMA chunk CC (rows [o][CC*256 + rl]) into LDS buffer BUF ----
    // Per iteration n: 256 threads x 16 B = 512 uint2. lin2 = n*512 + tid*2;
    // o = lin2>>8, rl = lin2&255. LDS dest (wave-uniform) element
    // n*512 + wave*128; HW adds lane*16 B -> element +lane*2 == lin2. MASKED
    // (chunk 3): only rl<96 valid; masked lanes skip (LDS garbage never read).
#define STAGE(CC, BUF, MASKED)                                                 \
    {                                                                          \
        const uint2* gch = Wp + j * (OO * RR) + (CC) * 256;                    \
        _Pragma("unroll")                                                      \
        for (int n = 0; n < 4; ++n) {                                          \
            const int lin2 = (n << 9) + (tid << 1);                            \
            const int o = lin2 >> 8;                                           \
            const int rl = lin2 & 255;                                         \
            if (!(MASKED) || rl < 96) {                                        \
                const uint2* gsrc = gch + o * RR + rl;                         \
                uint2* ldst = &wlds[BUF][(n << 9) + (wave << 7)];              \
                __builtin_amdgcn_global_load_lds(                              \
                    (const __attribute__((address_space(1))) uint32_t*)gsrc,   \
                    (__attribute__((address_space(3))) uint32_t*)ldst,         \
                    16, 0, 0);                                                 \
            }                                                                  \
        }                                                                      \
    }

    // ---- compute u_hat for chunk CC (KK k-slots) from LDS buffer BUF ----
#define COMPUTE(CC, BUF, KK)                                                   \
    {                                                                          \
        _Pragma("unroll")                                                      \
        for (int kl = 0; kl < (KK); ++kl) {                                    \
            const int rl = (kl << 6) + lane;                                   \
            const bool valid = ((CC) * 4 + kl < KMAX - 1) || (lane < 32);      \
            const int rloff = valid ? rl : 0;                                  \
            const uint2 uu = up[b * RR + (CC) * 256 + rloff];                  \
            float d[OO];                                                       \
            _Pragma("unroll")                                                  \
            for (int o = 0; o < OO; ++o) {                                     \
                const uint2 ww = wlds[BUF][(o << 8) + rl];                     \
                float t0 = __builtin_amdgcn_fdot2(bc_h2(ww.x), bc_h2(uu.x),    \
                                                  0.0f, false);                \
                d[o] = __builtin_amdgcn_fdot2(bc_h2(ww.y), bc_h2(uu.y), t0,    \
                                              false);                          \
            }                                                                  \
            _Pragma("unroll")                                                  \
            for (int o2 = 0; o2 < 4; ++o2)                                     \
                uh[(CC) * 4 + kl][o2] =                                        \
                    valid ? pack2(d[2 * o2], d[2 * o2 + 1]) : 0u;              \
        }                                                                      \
    }

    STAGE(0, 0, false)
    __syncthreads();           // drains chunk-0 DMA
    STAGE(1, 1, false)         // chunk-1 loads fly during compute(0)
    COMPUTE(0, 0, 4)
    __syncthreads();           // drains chunk-1 DMA; all waves done reading buf0
    STAGE(2, 0, false)
    COMPUTE(1, 1, 4)
    __syncthreads();
    STAGE(3, 1, true)
    COMPUTE(2, 0, 4)
    __syncthreads();
    COMPUTE(3, 1, 2)
#undef STAGE
#undef COMPUTE

    float V[OO];  // running sum of past v's (b_r = <uhat_r, V>)
    float v[OO];

    // ---- iteration 0: b=0 -> c uniform = 1/R (packed fp16 partial sums) ----
    {
        h2v accp[4];
#pragma unroll
        for (int o2 = 0; o2 < 4; ++o2) accp[o2] = bc_h2(uh[0][o2]);
#pragma unroll
        for (int k = 1; k < KMAX; ++k)
#pragma unroll
            for (int o2 = 0; o2 < 4; ++o2) accp[o2] += bc_h2(uh[k][o2]);

        float s[OO];
#pragma unroll
        for (int o2 = 0; o2 < 4; ++o2) {
            s[2 * o2]     = wave_sum((float)accp[o2].x) * (1.0f / (float)RR);
            s[2 * o2 + 1] = wave_sum((float)accp[o2].y) * (1.0f / (float)RR);
        }
        float n2 = 0.0f;
#pragma unroll
        for (int o = 0; o < OO; ++o) n2 += s[o] * s[o];
        const float scale = sqrtf(n2) / (1.0f + n2);
#pragma unroll
        for (int o = 0; o < OO; ++o) { v[o] = s[o] * scale; V[o] = v[o]; }
    }

    // ---- iterations 1 and 2 ----
#pragma unroll
    for (int it = 1; it < 3; ++it) {
        uint32_t Vp[4];
#pragma unroll
        for (int o2 = 0; o2 < 4; ++o2)
            Vp[o2] = pack2(V[2 * o2], V[2 * o2 + 1]);

        float zp = 0.0f;
        float sp[OO];
#pragma unroll
        for (int o = 0; o < OO; ++o) sp[o] = 0.0f;

#pragma unroll
        for (int k = 0; k < KMAX; ++k) {
            float br = 0.0f;
#pragma unroll
            for (int o2 = 0; o2 < 4; ++o2)
                br = __builtin_amdgcn_fdot2(bc_h2(uh[k][o2]), bc_h2(Vp[o2]),
                                            br, false);
            // mask invalid routes (k==13, lane>=32): exp(0)=1 would pollute Z
            const float e = (k < KMAX - 1 || lane < 32) ? __expf(br) : 0.0f;
            zp += e;
#pragma unroll
            for (int o2 = 0; o2 < 4; ++o2) {
                sp[2 * o2]     = fmaf(e, lo_f(uh[k][o2]), sp[2 * o2]);
                sp[2 * o2 + 1] = fmaf(e, hi_f(uh[k][o2]), sp[2 * o2 + 1]);
            }
        }
        const float invZ = 1.0f / wave_sum(zp);

        float s[OO];
#pragma unroll
        for (int o = 0; o < OO; ++o) s[o] = wave_sum(sp[o]) * invZ;

        float n2 = 0.0f;
#pragma unroll
        for (int o = 0; o < OO; ++o) n2 += s[o] * s[o];
        const float scale = sqrtf(n2) / (1.0f + n2);
#pragma unroll
        for (int o = 0; o < OO; ++o) v[o] = s[o] * scale;

        if (it < 2) {
#pragma unroll
            for (int o = 0; o < OO; ++o) V[o] += v[o];
        }
    }

    // ---- write out[b][j][o]; v replicated across lanes after butterflies ----
    float outv = 0.0f;
#pragma unroll
    for (int o = 0; o < OO; ++o)
        if (lane == o) outv = v[o];
    if (lane < OO) out[(b * JJ + j) * OO + lane] = outv;
}

extern "C" void kernel_launch(void* const* d_in, const int* in_sizes, int n_in,
                              void* d_out, int out_size, void* d_ws, size_t ws_size,
                              hipStream_t stream) {
    const float* u = (const float*)d_in[0];  // [128, 864, 4]
    const float* W = (const float*)d_in[1];  // [1, 166, 864, 8, 4]
    float* out = (float*)d_out;              // [128, 166, 8]

    uint2* Wp = (uint2*)d_ws;                          // 9,179,136 B
    uint2* up = (uint2*)((char*)d_ws + 9179136);       // +884,736 B (~10.1 MB total)

    pack_kernel<<<WBLOCKS + UBLOCKS, 256, 0, stream>>>(
        (const float4*)W, (const float4*)u, Wp, up);

    const int grid = JJ * (BB / 4);  // 5312 blocks, 4 waves each
    digitcaps_kernel<<<grid, 256, 0, stream>>>(Wp, up, out);
}